// Round 4
// baseline (441.603 us; speedup 1.0000x reference)
//
#include <hip/hip_runtime.h>
#include <hip/hip_bf16.h>
#include <hip/hip_cooperative_groups.h>

// Problem: out[b,j,k] = squash_j( s[b,j,k] ), s = sum_{i<2048,u<16} W[i,j,k,u] x[b,u,i]
// GEMM view: C[m=b(32), n=(j,k)(1024)] = A[m,(i,u)] B[(i,u),n], K=32768.
// W[i][j][k][u] strides (floats): i:16384, j:1024, k:16, u:1
// x[b][u][i]    strides (floats): b:32768, u:2048, i:1
//
// Fused single cooperative kernel: phase1 xprep -> grid.sync -> phase2 mfma
// (R0 config: KSPLIT=32, 1 j/block, unroll 4 — the best-measured core) ->
// grid.sync -> phase3 finish spread over all 512 blocks.
// Rationale: three mfma structures (R0/R2/R3) all land within +-2.5us ->
// mfma is BW-bound at the 134MB W stream (~21us); remaining ~16us of our
// ~46us budget is kernel-boundary ramp/drain + launch gaps, which fusion
// removes. 512 blocks x 256 thr = 2 blocks/CU, trivially co-resident.

#define B_SZ   32
#define IC     2048
#define NJ     16
#define NK     64
#define SOUT   (B_SZ*NJ*NK)      // 32768
#define KSTEPS 1024              // K-steps; each covers kdim=32 = (2 i's x 16 u)
#define KSPLIT 32                // K-splits (grid = NJ * KSPLIT = 512 blocks)
#define SPW    (KSTEPS/KSPLIT)   // 32 steps per block

typedef float v4f __attribute__((ext_vector_type(4)));
typedef short v8s __attribute__((ext_vector_type(8)));

// f32 -> bf16 round-to-nearest-even (bit trick)
static __device__ inline ushort f2bf(float f) {
    uint32_t u = __float_as_uint(f);
    u += 0x7FFFu + ((u >> 16) & 1u);
    return (ushort)(u >> 16);
}

__global__ __launch_bounds__(256)
void caps_fused(const float* __restrict__ x, const float* __restrict__ W,
                float* __restrict__ out, float* __restrict__ part,
                ushort* __restrict__ xb) {
    cooperative_groups::grid_group grid = cooperative_groups::this_grid();
    const int tid = threadIdx.x;
    const int bid = blockIdx.x;          // 0..511

    // ---------------------------------------------------------------
    // Phase 1: xprep — build A-fragments in bf16.
    // kk = q*8 + jj -> i_off = kk>>4, u = kk&15.
    // xb flat: [step(1024)][mt(2)][lane(64)][jj(8)] bf16; value =
    //   bf16( x[b = mt*16+(lane&15)][u = (q&1)*8+jj][i = 2*step+(q>>1)] )
    // 512 blocks * 256 thr = 131072 threads, exact coverage.
    // ---------------------------------------------------------------
    {
        int gid  = bid * 256 + tid;
        int lane = gid & 63;
        int mt   = (gid >> 6) & 1;
        int step = gid >> 7;
        int q    = lane >> 4;
        int b    = mt * 16 + (lane & 15);
        int i    = 2 * step + (q >> 1);
        int u0   = (q & 1) * 8;

        const float* xp = x + (size_t)b * (16 * IC) + (size_t)u0 * IC + i;
        ushort tmp[8];
        #pragma unroll
        for (int jj = 0; jj < 8; ++jj)
            tmp[jj] = f2bf(xp[(size_t)jj * IC]);
        *(v8s*)(xb + (size_t)gid * 8) = *(const v8s*)tmp;  // 16 B/lane coalesced
    }

    __threadfence();
    grid.sync();

    // ---------------------------------------------------------------
    // Phase 2: split-K MFMA (R0 core). block -> (j = bid&15, split = bid>>4).
    // 4 waves; wave wv = k'-tile. Per K-step: 2 W dwordx4 (read-once),
    // cvt->bf16 B-frag, 2 MFMA (two b-tiles). No LDS, no barriers.
    // B-operand layout: lane holds B[kk = (lane>>4)*8 + jj][n = lane&15];
    //   W addr: i = 2*step + (q>>1), u = (q&1)*8 + jj (8 consecutive floats).
    // ---------------------------------------------------------------
    {
        const int wv    = tid >> 6;
        const int lane  = tid & 63;
        const int j     = bid & (NJ - 1);
        const int split = bid >> 4;
        const int n     = lane & 15;
        const int q     = lane >> 4;
        const int step0 = split * SPW;

        v4f acc0 = {0.f, 0.f, 0.f, 0.f};
        v4f acc1 = {0.f, 0.f, 0.f, 0.f};

        const float*  wp = W + (size_t)(2 * step0 + (q >> 1)) * 16384
                             + (size_t)j * 1024 + (size_t)(wv * 16 + n) * 16 + (q & 1) * 8;
        const ushort* xp = xb + (size_t)step0 * 1024 + (size_t)lane * 8;

        #pragma unroll 4
        for (int s = 0; s < SPW; ++s) {
            v4f w0 = *(const v4f*)(wp);
            v4f w1 = *(const v4f*)(wp + 4);
            v8s a0 = *(const v8s*)(xp);          // b-tile 0 (b 0..15)
            v8s a1 = *(const v8s*)(xp + 512);    // b-tile 1 (b 16..31)
            v8s bb;
            bb[0] = (short)f2bf(w0.x); bb[1] = (short)f2bf(w0.y);
            bb[2] = (short)f2bf(w0.z); bb[3] = (short)f2bf(w0.w);
            bb[4] = (short)f2bf(w1.x); bb[5] = (short)f2bf(w1.y);
            bb[6] = (short)f2bf(w1.z); bb[7] = (short)f2bf(w1.w);
            acc0 = __builtin_amdgcn_mfma_f32_16x16x32_bf16(a0, bb, acc0, 0, 0, 0);
            acc1 = __builtin_amdgcn_mfma_f32_16x16x32_bf16(a1, bb, acc1, 0, 0, 0);
            wp += 2 * 16384;
            xp += 1024;
        }

        // C/D layout: col = lane&15 = n (k'), row = q*4 + reg = m (b).
        // part[split][b][j][k] : k = wv*16 + n
        float* pp = part + (size_t)split * SOUT + (size_t)j * NK + wv * 16 + n;
        #pragma unroll
        for (int r = 0; r < 4; ++r) {
            int m = q * 4 + r;
            pp[(size_t)m * 1024]        = acc0[r];
            pp[(size_t)(m + 16) * 1024] = acc1[r];
        }
    }

    __threadfence();
    grid.sync();

    // ---------------------------------------------------------------
    // Phase 3: sum K-splits + squash over j, spread over ALL 512 blocks.
    // block -> (b = bid>>4, k0 = (bid&15)*4); thread -> (jj, kc in 0..3,
    // sg in 0..3). Each thread sums 8 splits (sp = sg + 4*ss) -> LDS
    // reduce over sg -> squash over jj. 4x less per-thread load latency
    // than the old 128-block version.
    // ---------------------------------------------------------------
    {
        __shared__ float ls[256];
        __shared__ float l2[64];
        const int b  = bid >> 4;
        const int k0 = (bid & 15) * 4;
        const int jj = tid >> 4;
        const int kc = (tid >> 2) & 3;
        const int sg = tid & 3;
        const size_t idx = (size_t)b * 1024 + (size_t)jj * NK + k0 + kc;

        float s = 0.0f;
        #pragma unroll
        for (int ss = 0; ss < KSPLIT / 4; ++ss)
            s += part[(size_t)(sg + 4 * ss) * SOUT + idx];
        ls[tid] = s;
        __syncthreads();

        if (sg == 0) {
            float sa = ls[tid] + ls[tid + 1] + ls[tid + 2] + ls[tid + 3];
            l2[jj * 4 + kc] = sa;
        }
        __syncthreads();

        if (sg == 0) {
            float sa  = l2[jj * 4 + kc];
            float msq = 0.0f;
            #pragma unroll
            for (int j2 = 0; j2 < NJ; ++j2) {
                float v = l2[j2 * 4 + kc];
                msq += v * v;
            }
            float mag = sqrtf(msq);
            out[idx] = sa * (mag / (1.0f + msq));
        }
    }
}

extern "C" void kernel_launch(void* const* d_in, const int* in_sizes, int n_in,
                              void* d_out, int out_size, void* d_ws, size_t ws_size,
                              hipStream_t stream) {
    const float* x = (const float*)d_in[0];   // (32, 16, 2048) f32
    const float* W = (const float*)d_in[1];   // (1, 2048, 16, 64, 16) f32
    float* out  = (float*)d_out;              // (32, 16, 64) f32

    float*  part = (float*)d_ws;                            // 4 MB
    ushort* xb   = (ushort*)(part + (size_t)KSPLIT * SOUT); // 2 MB

    void* args[] = {(void*)&x, (void*)&W, (void*)&out, (void*)&part, (void*)&xb};
    hipLaunchCooperativeKernel((void*)caps_fused, dim3(NJ * KSPLIT), dim3(256),
                               args, 0, stream);
}

// Round 5
// 207.690 us; speedup vs baseline: 2.1263x; 2.1263x over previous
//
#include <hip/hip_runtime.h>
#include <hip/hip_bf16.h>

// Problem: out[b,j,k] = squash_j( s[b,j,k] ), s = sum_{i<2048,u<16} W[i,j,k,u] x[b,u,i]
// GEMM view: C[m=b(32), n=(j,k)(1024)] = A[m,(i,u)] B[(i,u),n], K=32768.
// W[i][j][k][u] strides (floats): i:16384, j:1024, k:16, u:1
// x[b][u][i]    strides (floats): b:32768, u:2048, i:1
//
// R5 structure: TWO kernels (was three).
//  - caps_main: per-block LDS staging of the A-fragment slice (replaces the
//    global xprep kernel + xb buffer; 16 j-blocks redundantly stage the same
//    split slice — x is 4MB, L2-resident, so redundancy is ~2us chip-wide),
//    then the proven R0 K-loop (KSPLIT=32, unroll 4, no nt).
//  - caps_finish: R4's 512-block spread reduction+squash (correctness-proven).
// No cooperative launch, no device-scope sync (R4 showed grid.sync spin
// collapses the memory system on this chip).

#define B_SZ   32
#define IC     2048
#define NJ     16
#define NK     64
#define SOUT   (B_SZ*NJ*NK)      // 32768
#define KSTEPS 1024              // K-steps; each covers kdim=32 = (2 i's x 16 u)
#define KSPLIT 32                // K-splits (grid = NJ x KSPLIT = 512 blocks)
#define SPW    (KSTEPS/KSPLIT)   // 32 steps per block

typedef float v4f __attribute__((ext_vector_type(4)));
typedef short v8s __attribute__((ext_vector_type(8)));

// f32 -> bf16 round-to-nearest-even (bit trick)
static __device__ inline ushort f2bf(float f) {
    uint32_t u = __float_as_uint(f);
    u += 0x7FFFu + ((u >> 16) & 1u);
    return (ushort)(u >> 16);
}

// ---------------------------------------------------------------------------
// caps_main: block = (j, split), 256 thr = 4 waves; wave wv = k'-tile (16 k's).
//
// Stage phase: build A-fragments for this split in LDS (64 KB):
//   axb[step(32)][mt(2)][lane(64)][jj(8)] bf16, value =
//     bf16( x[b = mt*16+(lane&15)][u = (q&1)*8+jj][i = 64*split + 2*step+(q>>1)] )
//   with q = lane>>4.  Work item w in [0,2048): row r=w>>2 -> (b=r>>4, u=r&15),
//   chunk c=w&3 -> 16 consecutive floats of x row.  Loads are 256B-contiguous
//   per 4-thread group (coalesced); scatter via ds_write u16 (one-time cost).
//
// K-loop (R0 core): per step 2 W dwordx4 (read-once stream), cvt->bf16 B-frag,
// a0/a1 from LDS (ds_read_b128, conflict-free), 2 MFMA. 64KB LDS -> 2 blk/CU.
// B-operand layout: lane holds B[kk = (lane>>4)*8 + jj][n = lane&15];
//   W addr: i = 2*step + (q>>1), u = (q&1)*8 + jj (8 consecutive floats).
// ---------------------------------------------------------------------------
__global__ __launch_bounds__(256)
void caps_main(const float* __restrict__ x, const float* __restrict__ W,
               float* __restrict__ part) {
    __shared__ ushort axb[SPW * 1024];   // 64 KB
    const int tid   = threadIdx.x;
    const int j     = blockIdx.x;        // 0..15
    const int split = blockIdx.y;        // 0..KSPLIT-1
    const int i0    = split * 64;

    // ---- stage x slice -> LDS A-fragments ----
    #pragma unroll
    for (int it = 0; it < 8; ++it) {
        int w = it * 256 + tid;          // 0..2047
        int r = w >> 2;                  // (b,u) row 0..511
        int c = w & 3;                   // 16-float chunk
        int b = r >> 4;
        int u = r & 15;
        const float* xp = x + (size_t)b * 32768 + (size_t)u * 2048 + i0 + c * 16;
        v4f f0 = *(const v4f*)(xp);
        v4f f1 = *(const v4f*)(xp + 4);
        v4f f2 = *(const v4f*)(xp + 8);
        v4f f3 = *(const v4f*)(xp + 12);
        float ff[16] = {f0.x, f0.y, f0.z, f0.w, f1.x, f1.y, f1.z, f1.w,
                        f2.x, f2.y, f2.z, f2.w, f3.x, f3.y, f3.z, f3.w};
        const int mtoff = (b >> 4) * 512;
        const int bl    = b & 15;
        const int qlo   = u >> 3;        // q&1
        const int jj    = u & 7;
        #pragma unroll
        for (int e = 0; e < 16; ++e) {
            int il   = c * 16 + e;                    // local i 0..63
            int q    = qlo | ((il & 1) << 1);
            int addr = (il >> 1) * 1024 + mtoff + ((bl | (q << 4)) * 8) + jj;
            axb[addr] = f2bf(ff[e]);
        }
    }
    __syncthreads();

    // ---- K-loop ----
    const int wv   = tid >> 6;
    const int lane = tid & 63;
    const int n    = lane & 15;
    const int q    = lane >> 4;
    const int step0 = split * SPW;

    v4f acc0 = {0.f, 0.f, 0.f, 0.f};
    v4f acc1 = {0.f, 0.f, 0.f, 0.f};

    const float* wp = W + (size_t)(2 * step0 + (q >> 1)) * 16384
                        + (size_t)j * 1024 + (size_t)(wv * 16 + n) * 16 + (q & 1) * 8;
    const ushort* xl = axb + lane * 8;

    #pragma unroll 4
    for (int s = 0; s < SPW; ++s) {
        v4f w0 = *(const v4f*)(wp);
        v4f w1 = *(const v4f*)(wp + 4);
        v8s a0 = *(const v8s*)(xl);          // b-tile 0 (b 0..15)
        v8s a1 = *(const v8s*)(xl + 512);    // b-tile 1 (b 16..31)
        v8s bb;
        bb[0] = (short)f2bf(w0.x); bb[1] = (short)f2bf(w0.y);
        bb[2] = (short)f2bf(w0.z); bb[3] = (short)f2bf(w0.w);
        bb[4] = (short)f2bf(w1.x); bb[5] = (short)f2bf(w1.y);
        bb[6] = (short)f2bf(w1.z); bb[7] = (short)f2bf(w1.w);
        acc0 = __builtin_amdgcn_mfma_f32_16x16x32_bf16(a0, bb, acc0, 0, 0, 0);
        acc1 = __builtin_amdgcn_mfma_f32_16x16x32_bf16(a1, bb, acc1, 0, 0, 0);
        wp += 2 * 16384;
        xl += 1024;
    }

    // C/D layout: col = lane&15 = n (k'), row = q*4 + reg = m (b).
    // part[split][b][j][k] : k = wv*16 + n
    float* pp = part + (size_t)split * SOUT + (size_t)j * NK + wv * 16 + n;
    #pragma unroll
    for (int r = 0; r < 4; ++r) {
        int m = q * 4 + r;
        pp[(size_t)m * 1024]        = acc0[r];
        pp[(size_t)(m + 16) * 1024] = acc1[r];
    }
}

// ---------------------------------------------------------------------------
// finish: sum K-splits + squash over j, spread over 512 blocks.
// block -> (b = bid>>4, k0 = (bid&15)*4); thread -> (jj = tid>>4,
// kc = (tid>>2)&3, sg = tid&3). Each thread sums 8 splits -> LDS reduce over
// sg -> squash over jj.
// ---------------------------------------------------------------------------
__global__ __launch_bounds__(256)
void caps_finish(const float* __restrict__ part, float* __restrict__ out) {
    __shared__ float ls[256];
    __shared__ float l2[64];
    const int bid = blockIdx.x;
    const int b   = bid >> 4;
    const int k0  = (bid & 15) * 4;
    const int tid = threadIdx.x;
    const int jj  = tid >> 4;
    const int kc  = (tid >> 2) & 3;
    const int sg  = tid & 3;
    const size_t idx = (size_t)b * 1024 + (size_t)jj * NK + k0 + kc;

    float s = 0.0f;
    #pragma unroll
    for (int ss = 0; ss < KSPLIT / 4; ++ss)
        s += part[(size_t)(sg + 4 * ss) * SOUT + idx];
    ls[tid] = s;
    __syncthreads();

    if (sg == 0)
        l2[jj * 4 + kc] = ls[tid] + ls[tid + 1] + ls[tid + 2] + ls[tid + 3];
    __syncthreads();

    if (sg == 0) {
        float sa  = l2[jj * 4 + kc];
        float msq = 0.0f;
        #pragma unroll
        for (int j2 = 0; j2 < NJ; ++j2) {
            float v = l2[j2 * 4 + kc];
            msq += v * v;
        }
        float mag = sqrtf(msq);
        out[idx] = sa * (mag / (1.0f + msq));
    }
}

extern "C" void kernel_launch(void* const* d_in, const int* in_sizes, int n_in,
                              void* d_out, int out_size, void* d_ws, size_t ws_size,
                              hipStream_t stream) {
    const float* x = (const float*)d_in[0];   // (32, 16, 2048) f32
    const float* W = (const float*)d_in[1];   // (1, 2048, 16, 64, 16) f32
    float* out  = (float*)d_out;              // (32, 16, 64) f32

    float* part = (float*)d_ws;               // 4 MB

    caps_main  <<<dim3(NJ, KSPLIT), 256, 0, stream>>>(x, W, part);
    caps_finish<<<512,              256, 0, stream>>>(part, out);
}

// Round 7
// 201.625 us; speedup vs baseline: 2.1902x; 1.0301x over previous
//
#include <hip/hip_runtime.h>
#include <hip/hip_bf16.h>

// Problem: out[b,j,k] = squash_j( s[b,j,k] ), s = sum_{i<2048,u<16} W[i,j,k,u] x[b,u,i]
// GEMM view: C[m=b(32), n=(j,k)(1024)] = A[m,(i,u)] B[(i,u),n], K=32768.
// W[i][j][k][u] strides (floats): i:16384, j:1024, k:16, u:1
// x[b][u][i]    strides (floats): b:32768, u:2048, i:1
//
// R7 (= R6 with compile fix): R0's proven 3-kernel structure, with:
//  - xprep v2: full-cache-line x reads + LDS transpose (kills the 16x line
//    amplification of the old 4B-stride-8KB gather), coalesced xb writes.
//  - packed bf16 conversion (__float22bfloat162_rn -> v_cvt_pk_bf16_f32)
//    in both xprep and the K-loop (was ~3 VALU ops/element bit-trick).
//  - finish spread over 512 blocks (was 128 = 0.5 blocks/CU).
// R2/R3 established the K-loop is not concurrency-bound; R5 established
// in-kernel scatter staging is a loss. KSPLIT=32, unroll 4, no nt.

#define B_SZ   32
#define IC     2048
#define NJ     16
#define NK     64
#define SOUT   (B_SZ*NJ*NK)      // 32768
#define KSTEPS 1024              // K-steps; each covers kdim=32 = (2 i's x 16 u)
#define KSPLIT 32                // K-splits (grid = NJ x KSPLIT = 512 blocks)
#define SPW    (KSTEPS/KSPLIT)   // 32 steps per block

typedef float  v4f __attribute__((ext_vector_type(4)));
typedef short  v8s __attribute__((ext_vector_type(8)));
typedef uint   v4u __attribute__((ext_vector_type(4)));

// pack 2 f32 -> 1 dword of 2 bf16 (RNE); lowers to v_cvt_pk_bf16_f32
static __device__ inline uint pk2(float a, float b) {
    __hip_bfloat162 h = __float22bfloat162_rn(make_float2(a, b));
    uint r;
    __builtin_memcpy(&r, &h, 4);
    return r;
}

// ---------------------------------------------------------------------------
// xprep v2: build A-fragments in bf16 with line-efficient reads.
// xb flat: [step(1024)][mt(2)][lane(64)][jj(8)] bf16; value =
//   bf16( x[b = mt*16+(lane&15)][u = (q&1)*8+jj][i = 2*step+(q>>1)] ), q=lane>>4.
// Grid (128, 2): block = (i-chunk of 16, mt). Phase 1: 256 threads each load
// one x row-chunk (16 consecutive floats = one 64B line, fully used), cvt_pk,
// stage to LDS tile[r2(256)][il(16)+2pad] with XOR swizzle (conflict-free
// writes, ~4-way reads). Phase 2: emit xb coalesced (16 B/lane v8s stores).
// ---------------------------------------------------------------------------
__global__ __launch_bounds__(256)
void caps_xprep(const float* __restrict__ x, ushort* __restrict__ xb) {
    __shared__ ushort tile[256 * 18];    // 9 KB
    const int t  = threadIdx.x;
    const int i0 = blockIdx.x * 16;      // 0..2032
    const int mt = blockIdx.y;           // 0..1

    // ---- load + convert + stage ----
    {
        const int r2 = t;                          // row = b_local*16 + u
        const float* xp = x + (size_t)(mt * 256 + r2) * IC + i0;
        v4f f0 = *(const v4f*)(xp);
        v4f f1 = *(const v4f*)(xp + 4);
        v4f f2 = *(const v4f*)(xp + 8);
        v4f f3 = *(const v4f*)(xp + 12);
        uint d[8] = {pk2(f0.x, f0.y), pk2(f0.z, f0.w), pk2(f1.x, f1.y), pk2(f1.z, f1.w),
                     pk2(f2.x, f2.y), pk2(f2.z, f2.w), pk2(f3.x, f3.y), pk2(f3.z, f3.w)};
        const int swz = ((r2 >> 3) & 7) << 1;      // even -> dword pairs stay intact
        #pragma unroll
        for (int c = 0; c < 8; ++c)
            *(uint*)&tile[r2 * 18 + ((2 * c) ^ swz)] = d[c];
    }
    __syncthreads();

    // ---- emit coalesced xb ----
    #pragma unroll
    for (int rr = 0; rr < 2; ++rr) {
        const int idx   = rr * 256 + t;
        const int stepl = idx >> 6;                // 0..7
        const int lane  = idx & 63;
        const int q  = lane >> 4;
        const int bl = lane & 15;
        const int il = 2 * stepl + (q >> 1);       // 0..15
        const int rb = bl * 16 + (q & 1) * 8;      // row base (mult of 8)
        const int swz = ((rb >> 3) & 7) << 1;      // constant over jj
        ushort v[8];
        #pragma unroll
        for (int jj = 0; jj < 8; ++jj)
            v[jj] = tile[(rb + jj) * 18 + (il ^ swz)];
        const int stepg = blockIdx.x * 8 + stepl;
        *(v8s*)(xb + (size_t)stepg * 1024 + mt * 512 + lane * 8) = *(const v8s*)v;
    }
}

// ---------------------------------------------------------------------------
// main: block = (j, split), 256 thr = 4 waves; wave wv = k'-tile (16 k's).
// Per K-step: 2 W dwordx4 (read-once stream), cvt_pk->bf16 B-frag, 2 MFMA.
// No LDS, no barriers. (R0 core — proven best across R0/R2/R3/R5.)
// B-operand layout: lane holds B[kk = (lane>>4)*8 + jj][n = lane&15];
//   W addr: i = 2*step + (q>>1), u = (q&1)*8 + jj (8 consecutive floats).
// ---------------------------------------------------------------------------
__global__ __launch_bounds__(256)
void caps_mfma(const ushort* __restrict__ xb, const float* __restrict__ W,
               float* __restrict__ part) {
    const int tid   = threadIdx.x;
    const int wv    = tid >> 6;       // k'-tile 0..3
    const int lane  = tid & 63;
    const int j     = blockIdx.x;     // 0..15
    const int split = blockIdx.y;     // 0..KSPLIT-1
    const int n     = lane & 15;
    const int q     = lane >> 4;
    const int step0 = split * SPW;

    v4f acc0 = {0.f, 0.f, 0.f, 0.f};
    v4f acc1 = {0.f, 0.f, 0.f, 0.f};

    const float*  wp = W + (size_t)(2 * step0 + (q >> 1)) * 16384
                         + (size_t)j * 1024 + (size_t)(wv * 16 + n) * 16 + (q & 1) * 8;
    const ushort* xp = xb + (size_t)step0 * 1024 + (size_t)lane * 8;

    #pragma unroll 4
    for (int s = 0; s < SPW; ++s) {
        v4f w0 = *(const v4f*)(wp);
        v4f w1 = *(const v4f*)(wp + 4);
        v8s a0 = *(const v8s*)(xp);          // b-tile 0 (b 0..15)
        v8s a1 = *(const v8s*)(xp + 512);    // b-tile 1 (b 16..31)
        v4u bu;
        bu[0] = pk2(w0.x, w0.y);
        bu[1] = pk2(w0.z, w0.w);
        bu[2] = pk2(w1.x, w1.y);
        bu[3] = pk2(w1.z, w1.w);
        v8s bb;
        __builtin_memcpy(&bb, &bu, 16);
        acc0 = __builtin_amdgcn_mfma_f32_16x16x32_bf16(a0, bb, acc0, 0, 0, 0);
        acc1 = __builtin_amdgcn_mfma_f32_16x16x32_bf16(a1, bb, acc1, 0, 0, 0);
        wp += 2 * 16384;
        xp += 1024;
    }

    // C/D layout: col = lane&15 = n (k'), row = q*4 + reg = m (b).
    // part[split][b][j][k] : k = wv*16 + n
    float* pp = part + (size_t)split * SOUT + (size_t)j * NK + wv * 16 + n;
    #pragma unroll
    for (int r = 0; r < 4; ++r) {
        int m = q * 4 + r;
        pp[(size_t)m * 1024]        = acc0[r];
        pp[(size_t)(m + 16) * 1024] = acc1[r];
    }
}

// ---------------------------------------------------------------------------
// finish: sum K-splits + squash over j, spread over 512 blocks.
// block -> (b = bid>>4, k0 = (bid&15)*4); thread -> (jj = tid>>4,
// kc = (tid>>2)&3, sg = tid&3). Each thread sums 8 splits -> LDS reduce over
// sg -> squash over jj.
// ---------------------------------------------------------------------------
__global__ __launch_bounds__(256)
void caps_finish(const float* __restrict__ part, float* __restrict__ out) {
    __shared__ float ls[256];
    __shared__ float l2[64];
    const int bid = blockIdx.x;
    const int b   = bid >> 4;
    const int k0  = (bid & 15) * 4;
    const int tid = threadIdx.x;
    const int jj  = tid >> 4;
    const int kc  = (tid >> 2) & 3;
    const int sg  = tid & 3;
    const size_t idx = (size_t)b * 1024 + (size_t)jj * NK + k0 + kc;

    float s = 0.0f;
    #pragma unroll
    for (int ss = 0; ss < KSPLIT / 4; ++ss)
        s += part[(size_t)(sg + 4 * ss) * SOUT + idx];
    ls[tid] = s;
    __syncthreads();

    if (sg == 0)
        l2[jj * 4 + kc] = ls[tid] + ls[tid + 1] + ls[tid + 2] + ls[tid + 3];
    __syncthreads();

    if (sg == 0) {
        float sa  = l2[jj * 4 + kc];
        float msq = 0.0f;
        #pragma unroll
        for (int j2 = 0; j2 < NJ; ++j2) {
            float v = l2[j2 * 4 + kc];
            msq += v * v;
        }
        float mag = sqrtf(msq);
        out[idx] = sa * (mag / (1.0f + msq));
    }
}

extern "C" void kernel_launch(void* const* d_in, const int* in_sizes, int n_in,
                              void* d_out, int out_size, void* d_ws, size_t ws_size,
                              hipStream_t stream) {
    const float* x = (const float*)d_in[0];   // (32, 16, 2048) f32
    const float* W = (const float*)d_in[1];   // (1, 2048, 16, 64, 16) f32
    float* out  = (float*)d_out;              // (32, 16, 64) f32

    float*  part = (float*)d_ws;                            // 4 MB
    ushort* xb   = (ushort*)(part + (size_t)KSPLIT * SOUT); // 2 MB

    caps_xprep <<<dim3(128, 2),     256, 0, stream>>>(x, xb);
    caps_mfma  <<<dim3(NJ, KSPLIT), 256, 0, stream>>>(xb, W, part);
    caps_finish<<<512,              256, 0, stream>>>(part, out);
}